// Round 9
// baseline (1319.252 us; speedup 1.0000x reference)
//
#include <hip/hip_runtime.h>
#include <math.h>

#define NLVL 16
#define MAX_ENTRY (1 << 19)
#define NPTS (1 << 20)

typedef float f2_t __attribute__((ext_vector_type(2)));
typedef float f4_t __attribute__((ext_vector_type(4)));

__device__ __forceinline__ void nt_store4(float4 v, float4* p) {
    f4_t t; t.x = v.x; t.y = v.y; t.z = v.z; t.w = v.w;
    __builtin_nontemporal_store(t, (f4_t*)p);
}
__device__ __forceinline__ void nt_storeu(unsigned v, unsigned* p) {
    __builtin_nontemporal_store(v, p);
}
__device__ __forceinline__ float2 nt_load2(const float2* p) {
    f2_t t = __builtin_nontemporal_load((const f2_t*)p);
    return make_float2(t.x, t.y);
}
__device__ __forceinline__ float4 nt_load4(const float4* p) {
    f4_t t = __builtin_nontemporal_load((const f4_t*)p);
    return make_float4(t.x, t.y, t.z, t.w);
}
__device__ __forceinline__ unsigned nt_loadu(const unsigned* p) {
    return __builtin_nontemporal_load(p);
}

// round-to-nearest-even f32 -> bf16 pair packed in u32 (a low, b high)
__device__ __forceinline__ unsigned pack_bf16(float a, float b) {
    unsigned ua = __float_as_uint(a), ub = __float_as_uint(b);
    ua = (ua + 0x7FFFu + ((ua >> 16) & 1u)) >> 16;
    ub = (ub + 0x7FFFu + ((ub >> 16) & 1u)) >> 16;
    return ua | (ub << 16);
}
__device__ __forceinline__ float bf_lo(unsigned u) { return __uint_as_float(u << 16); }
__device__ __forceinline__ float bf_hi(unsigned u) { return __uint_as_float(u & 0xFFFF0000u); }

// OFFSETS table from the reference (NOT binary order); weights in binary order.
__device__ __constant__ int OX[8] = {0, 0, 0, 0, 1, 1, 1, 1};
__device__ __constant__ int OY[8] = {0, 1, 0, 1, 0, 0, 1, 1};
__device__ __constant__ int OZ[8] = {0, 0, 1, 1, 0, 1, 0, 1};

__device__ __forceinline__ void corner_setup(
    float x0, float x1, float x2, float s, float hi,
    int& cx, int& cy, int& cz,
    float (&wx)[2], float (&wy)[2], float (&wz)[2])
{
    float c0 = fminf(fmaxf(x0 * s, 0.0f), hi);
    float c1 = fminf(fmaxf(x1 * s, 0.0f), hi);
    float c2 = fminf(fmaxf(x2 * s, 0.0f), hi);
    float f0 = floorf(c0), f1 = floorf(c1), f2 = floorf(c2);
    cx = (int)f0; cy = (int)f1; cz = (int)f2;
    float xx = c0 - f0, yy = c1 - f1, zz = c2 - f2;
    wx[0] = 1.0f - xx; wx[1] = xx;
    wy[0] = 1.0f - yy; wy[1] = yy;
    wz[0] = 1.0f - zz; wz[1] = zz;
}

// bug-compatible pair accumulate: pair j = {E(0, j&1, j>>1), E(1, j&1, j>>1)}
__device__ __forceinline__ void acc_pair(
    int j, float4 f, const float (&wx)[2], const float (&wy)[2], const float (&wz)[2],
    float& a0, float& a1)
{
    const float w0 = wx[j & 1] * wy[j >> 1] * wz[0];
    const float w1 = wx[j >> 1] * wy[j & 1] * wz[1];
    a0 += w0 * f.x + w1 * f.z;
    a1 += w0 * f.y + w1 * f.w;
}

struct OptP {
    int   res[NLVL];
    int   res2[NLVL];
    float scale[NLVL];
    float hi[NLVL];
    int   cdim1, cdim2, cdim3;
};

// ======================= optimized path =======================

__global__ __launch_bounds__(256) void repack2_kernel(
    const float* __restrict__ x,
    const float* __restrict__ tables,
    float4* __restrict__ blk1,
    float4* __restrict__ blk2,
    float4* __restrict__ blk3,
    float4* __restrict__ xp,
    OptP P)
{
    const long long stride = (long long)gridDim.x * 256;
    const long long tid = (long long)blockIdx.x * 256 + threadIdx.x;

#pragma unroll
    for (int l = 1; l <= 2; ++l) {
        const int res = P.res[l], res2v = P.res2[l];
        const int cdim = res - 1;
        const long long ncell = (long long)cdim * cdim * cdim;
        const float2* tab = (const float2*)(tables + (size_t)l * MAX_ENTRY * 2);
        float4* dst = (l == 1) ? blk1 : blk2;
        for (long long c = tid; c < ncell; c += stride) {
            const int cx = (int)(c % cdim);
            const int cy = (int)((c / cdim) % cdim);
            const int cz = (int)(c / ((long long)cdim * cdim));
            const int base = cx + cy * res + cz * res2v;
#pragma unroll
            for (int j = 0; j < 4; ++j) {
                const int oy = j & 1, oz = j >> 1;
                const float2 e0 = tab[base + oy * res + oz * res2v];
                const float2 e1 = tab[base + 1 + oy * res + oz * res2v];
                nt_store4(make_float4(e0.x, e0.y, e1.x, e1.y), &dst[c * 4 + j]);
            }
        }
    }

    {
        const int res = P.res[3], res2v = P.res2[3];
        const int cdim = P.cdim3;
        const long long nblk = (long long)cdim * cdim * res;
        const float2* tab = (const float2*)(tables + (size_t)3 * MAX_ENTRY * 2);
        for (long long b = tid; b < nblk; b += stride) {
            const int bx = (int)(b % cdim);
            const int by = (int)((b / cdim) % cdim);
            const int z  = (int)(b / ((long long)cdim * cdim));
            const int base = bx + by * res + z * res2v;
#pragma unroll
            for (int oy = 0; oy < 2; ++oy) {
                const float2 e0 = tab[base + oy * res];
                const float2 e1 = tab[base + 1 + oy * res];
                nt_store4(make_float4(e0.x, e0.y, e1.x, e1.y), &blk3[b * 2 + oy]);
            }
        }
    }

    for (long long i = tid; i < NPTS; i += stride) {
        xp[i] = make_float4(x[3 * i + 0], x[3 * i + 1], x[3 * i + 2], 0.0f);
    }
}

// Pass A: levels 0 (LDS), 1, 2 (8-blocked, 1 line each, nt gathers). bf16 out.
__global__ __launch_bounds__(256) void passA_kernel(
    const float4* __restrict__ xp,
    const float* __restrict__ tables,
    const float4* __restrict__ blk1,
    const float4* __restrict__ blk2,
    unsigned* __restrict__ fb,
    OptP P)
{
    __shared__ float2 lds0[4096];
    {
        const float2* tab0 = (const float2*)tables;
        for (int j = threadIdx.x; j < 4096; j += 256) lds0[j] = tab0[j];
    }
    __syncthreads();

    const int i = blockIdx.x * 256 + threadIdx.x;

    const float4 v = nt_load4(&xp[i]);
    const float x0 = v.x, x1 = v.y, x2 = v.z;

    {
        int cx, cy, cz;
        float wx[2], wy[2], wz[2];
        corner_setup(x0, x1, x2, P.scale[0], P.hi[0], cx, cy, cz, wx, wy, wz);
        const int res = P.res[0], res2v = P.res2[0];
        const int base = cx + cy * res + cz * res2v;
        float a0 = 0.0f, a1 = 0.0f;
#pragma unroll
        for (int k = 0; k < 8; ++k) {
            const int idx = base + OX[k] + OY[k] * res + OZ[k] * res2v;
            const float2 f = lds0[idx];
            const float w = wx[k & 1] * wy[(k >> 1) & 1] * wz[k >> 2];
            a0 += w * f.x; a1 += w * f.y;
        }
        nt_storeu(pack_bf16(a0, a1), &fb[i]);
    }

#pragma unroll
    for (int l = 1; l <= 2; ++l) {
        int cx, cy, cz;
        float wx[2], wy[2], wz[2];
        corner_setup(x0, x1, x2, P.scale[l], P.hi[l], cx, cy, cz, wx, wy, wz);
        const int cdim = (l == 1) ? P.cdim1 : P.cdim2;
        const float4* blk = (l == 1) ? blk1 : blk2;
        const long long c = cx + (long long)cy * cdim + (long long)cz * cdim * cdim;
        float a0 = 0.0f, a1 = 0.0f;
#pragma unroll
        for (int j = 0; j < 4; ++j) {
            const float4 f = nt_load4(&blk[c * 4 + j]);
            acc_pair(j, f, wx, wy, wz, a0, a1);
        }
        nt_storeu(pack_bf16(a0, a1), &fb[(size_t)l * NPTS + i]);
    }
}

// Mega kernel: seg 0 -> L3 (2x2x1 blocks), seg 1,2 -> L4,L5, seg 3..12 -> hash.
// 2 points/thread; ALL table/blk gathers use nt (no-allocate experiment).
__global__ __launch_bounds__(256) void mega_kernel(
    const float4* __restrict__ xp,
    const float* __restrict__ tables,
    const float4* __restrict__ blk3,
    unsigned* __restrict__ fb,
    OptP P)
{
    const int seg = blockIdx.x >> 11;
    const int lvl = seg + 3;
    const int t = (blockIdx.x & 2047) * 256 + threadIdx.x;
    unsigned* fbl = fb + (size_t)lvl * NPTS;

    const float scale = P.scale[lvl], hiv = P.hi[lvl];

#pragma unroll
    for (int h = 0; h < 2; ++h) {
        const int i = t + h * (NPTS / 2);
        const float4 v = nt_load4(&xp[i]);
        int cx, cy, cz;
        float wx[2], wy[2], wz[2];
        corner_setup(v.x, v.y, v.z, scale, hiv, cx, cy, cz, wx, wy, wz);

        float a0 = 0.0f, a1 = 0.0f;

        if (lvl == 3) {
            const int cdim = P.cdim3;
            const long long b0 = cx + (long long)cy * cdim + (long long)cz * cdim * cdim;
            const long long b1 = b0 + (long long)cdim * cdim;
#pragma unroll
            for (int oz = 0; oz < 2; ++oz) {
                const long long b = (oz == 0) ? b0 : b1;
#pragma unroll
                for (int oy = 0; oy < 2; ++oy) {
                    const float4 f = nt_load4(&blk3[b * 2 + oy]);
                    acc_pair(oy + 2 * oz, f, wx, wy, wz, a0, a1);
                }
            }
        } else if (lvl < 6) {
            const int res = P.res[lvl], res2v = P.res2[lvl];
            const float2* tab = (const float2*)tables + (size_t)lvl * MAX_ENTRY;
            const int base = cx + cy * res + cz * res2v;
#pragma unroll
            for (int j = 0; j < 4; ++j) {
                const int idx = base + (j & 1) * res + (j >> 1) * res2v;
                const float2 flo = nt_load2(&tab[idx]);
                const float2 fhi = nt_load2(&tab[idx + 1]);
                acc_pair(j, make_float4(flo.x, flo.y, fhi.x, fhi.y), wx, wy, wz, a0, a1);
            }
        } else {
            const float2* tab = (const float2*)tables + (size_t)lvl * MAX_ENTRY;
            const unsigned P0 = 3367900313u, P1 = 2654435761u, P2 = 805459861u;
            unsigned hx[2], hy[2], hz[2];
            hx[0] = (unsigned)cx * P0; hx[1] = hx[0] + P0;
            hy[0] = (unsigned)cy * P1; hy[1] = hy[0] + P1;
            hz[0] = (unsigned)cz * P2; hz[1] = hz[0] + P2;
#pragma unroll
            for (int k = 0; k < 8; ++k) {
                const unsigned idx = (hx[OX[k]] ^ hy[OY[k]] ^ hz[OZ[k]]) & (MAX_ENTRY - 1);
                const float2 f = nt_load2(&tab[idx]);
                const float w = wx[k & 1] * wy[(k >> 1) & 1] * wz[k >> 2];
                a0 += w * f.x; a1 += w * f.y;
            }
        }

        nt_storeu(pack_bf16(a0, a1), &fbl[i]);
    }
}

// LDS-transpose assemble: coalesced reads of 16 streams, coalesced out writes.
// Block handles 512 points. LDS stride 514 (mod 32 == 2 -> <=2-way conflicts).
#define ASM_PTS 512
#define ASM_STRIDE 514
__global__ __launch_bounds__(256) void assemble_t_kernel(
    const unsigned* __restrict__ fb, float4* __restrict__ out)
{
    __shared__ unsigned lds[NLVL * ASM_STRIDE];
    const int base = blockIdx.x * ASM_PTS;
    const int tid = threadIdx.x;

#pragma unroll
    for (int l = 0; l < NLVL; ++l) {
        lds[l * ASM_STRIDE + tid]       = nt_loadu(&fb[(size_t)l * NPTS + base + tid]);
        lds[l * ASM_STRIDE + 256 + tid] = nt_loadu(&fb[(size_t)l * NPTS + base + 256 + tid]);
    }
    __syncthreads();

    float4* o4 = out + (size_t)base * 8;
#pragma unroll
    for (int j = 0; j < 16; ++j) {
        const int g = j * 256 + tid;          // 0 .. 4095
        const int p = g >> 3;
        const int c = g & 7;
        const unsigned u0 = lds[(2 * c) * ASM_STRIDE + p];
        const unsigned u1 = lds[(2 * c + 1) * ASM_STRIDE + p];
        nt_store4(make_float4(bf_lo(u0), bf_hi(u0), bf_lo(u1), bf_hi(u1)), &o4[g]);
    }
}

// ======================= fallback path (round-2, known-good) =======================

struct DenseParams {
    int   res[6];
    int   res2[6];
    float scale[6];
    float hi[6];
    long long tab_off[6];
};

__device__ __forceinline__ float2 hash_point_fb(
    float x0, float x1, float x2, const float2* __restrict__ tab,
    float scale, float hi)
{
    int cx, cy, cz;
    float wx[2], wy[2], wz[2];
    corner_setup(x0, x1, x2, scale, hi, cx, cy, cz, wx, wy, wz);
    const unsigned P0 = 3367900313u, P1 = 2654435761u, P2 = 805459861u;
    unsigned hx[2], hy[2], hz[2];
    hx[0] = (unsigned)cx * P0; hx[1] = hx[0] + P0;
    hy[0] = (unsigned)cy * P1; hy[1] = hy[0] + P1;
    hz[0] = (unsigned)cz * P2; hz[1] = hz[0] + P2;
    float a0 = 0.0f, a1 = 0.0f;
#pragma unroll
    for (int k = 0; k < 8; ++k) {
        const unsigned idx = (hx[OX[k]] ^ hy[OY[k]] ^ hz[OZ[k]]) & (MAX_ENTRY - 1);
        const float2 f = tab[idx];
        const float w = wx[k & 1] * wy[(k >> 1) & 1] * wz[k >> 2];
        a0 += w * f.x; a1 += w * f.y;
    }
    return make_float2(a0, a1);
}

__global__ __launch_bounds__(256) void dense6_kernel(
    const float* __restrict__ x,
    const float* __restrict__ tables,
    float* __restrict__ out,
    DenseParams P)
{
    const int i = blockIdx.x * 256 + threadIdx.x;
    if (i >= NPTS) return;
    const float x0 = x[3 * i + 0];
    const float x1 = x[3 * i + 1];
    const float x2 = x[3 * i + 2];
    float o[12];
#pragma unroll
    for (int l = 0; l < 6; ++l) {
        int cx, cy, cz;
        float wx[2], wy[2], wz[2];
        corner_setup(x0, x1, x2, P.scale[l], P.hi[l], cx, cy, cz, wx, wy, wz);
        const float2* tab = (const float2*)(tables + P.tab_off[l]);
        const int res  = P.res[l];
        const int res2 = P.res2[l];
        const int base = cx + cy * res + cz * res2;
        float a0 = 0.0f, a1 = 0.0f;
#pragma unroll
        for (int k = 0; k < 8; ++k) {
            const int idx = base + OX[k] + OY[k] * res + OZ[k] * res2;
            const float2 f = tab[idx];
            const float w = wx[k & 1] * wy[(k >> 1) & 1] * wz[k >> 2];
            a0 += w * f.x; a1 += w * f.y;
        }
        o[2 * l + 0] = a0; o[2 * l + 1] = a1;
    }
    float4* op = (float4*)(out + (size_t)i * 32);
    op[0] = ((float4*)o)[0];
    op[1] = ((float4*)o)[1];
    op[2] = ((float4*)o)[2];
}

__global__ __launch_bounds__(256) void hash_level_kernel(
    const float* __restrict__ x,
    const float* __restrict__ tables,
    float* __restrict__ out,
    int level, float scale, float hi)
{
    const int i = blockIdx.x * 256 + threadIdx.x;
    if (i >= NPTS) return;
    const float2* tab = (const float2*)tables + (size_t)level * MAX_ENTRY;
    const float2 r = hash_point_fb(x[3 * i], x[3 * i + 1], x[3 * i + 2], tab, scale, hi);
    *(float2*)(out + (size_t)i * 32 + 2 * level) = r;
}

__global__ __launch_bounds__(256) void generic_level_kernel(
    const float* __restrict__ x,
    const float* __restrict__ tables,
    float* __restrict__ out,
    int level, int res, int res2, int use_hash, float scale, float hi)
{
    const int i = blockIdx.x * 256 + threadIdx.x;
    if (i >= NPTS) return;
    const float x0 = x[3 * i + 0];
    const float x1 = x[3 * i + 1];
    const float x2 = x[3 * i + 2];
    int cx, cy, cz;
    float wx[2], wy[2], wz[2];
    corner_setup(x0, x1, x2, scale, hi, cx, cy, cz, wx, wy, wz);
    const float2* tab = (const float2*)tables + (size_t)level * MAX_ENTRY;
    float a0 = 0.0f, a1 = 0.0f;
    if (use_hash) {
        const unsigned P0 = 3367900313u, P1 = 2654435761u, P2 = 805459861u;
        unsigned hx[2], hy[2], hz[2];
        hx[0] = (unsigned)cx * P0; hx[1] = hx[0] + P0;
        hy[0] = (unsigned)cy * P1; hy[1] = hy[0] + P1;
        hz[0] = (unsigned)cz * P2; hz[1] = hz[0] + P2;
#pragma unroll
        for (int k = 0; k < 8; ++k) {
            const unsigned idx = (hx[OX[k]] ^ hy[OY[k]] ^ hz[OZ[k]]) & (MAX_ENTRY - 1);
            const float2 f = tab[idx];
            const float w = wx[k & 1] * wy[(k >> 1) & 1] * wz[k >> 2];
            a0 += w * f.x; a1 += w * f.y;
        }
    } else {
        const int base = cx + cy * res + cz * res2;
#pragma unroll
        for (int k = 0; k < 8; ++k) {
            const int idx = base + OX[k] + OY[k] * res + OZ[k] * res2;
            const float2 f = tab[idx];
            const float w = wx[k & 1] * wy[(k >> 1) & 1] * wz[k >> 2];
            a0 += w * f.x; a1 += w * f.y;
        }
    }
    *(float2*)(out + (size_t)i * 32 + 2 * level) = make_float2(a0, a1);
}

// ======================= launch =======================

extern "C" void kernel_launch(void* const* d_in, const int* in_sizes, int n_in,
                              void* d_out, int out_size, void* d_ws, size_t ws_size,
                              hipStream_t stream)
{
    const float* x      = (const float*)d_in[0];
    const float* tables = (const float*)d_in[1];
    float* out          = (float*)d_out;

    // Reproduce numpy's resolution computation bit-for-bit (same libm).
    int   res[NLVL], res2[NLVL], use_hash[NLVL];
    float scale[NLVL], hi[NLVL];
    const double b = exp((log(2048.0) - log(16.0)) / 15.0);
    for (int l = 0; l < NLVL; ++l) {
        const int r = (int)floor(16.0 * pow(b, (double)l));
        res[l]  = r;
        res2[l] = r * r;
        const long long t3 = (long long)r * r * r;
        use_hash[l] = (t3 >= (long long)MAX_ENTRY) ? 1 : 0;
        scale[l] = (float)(r - 1);
        hi[l]    = (float)((double)r - 1.0001);
    }

    const int block = 256;
    const int grid  = (NPTS + block - 1) / block;

    bool expected = true;
    for (int l = 0; l < 6; ++l)    expected = expected && !use_hash[l];
    for (int l = 6; l < NLVL; ++l) expected = expected && use_hash[l];
    expected = expected && (res[0] * res[0] * res[0] <= 4096);

    // Workspace layout: blk1 | blk2 | blk3 | xp | feat_bf16
    const int cdim1 = res[1] - 1, cdim2 = res[2] - 1, cdim3 = res[3] - 1;
    const size_t sz1 = (size_t)cdim1 * cdim1 * cdim1 * 64;
    const size_t sz2 = (size_t)cdim2 * cdim2 * cdim2 * 64;
    const size_t sz3 = (size_t)cdim3 * cdim3 * res[3] * 32;
    auto al = [](size_t v) { return (v + 255) & ~(size_t)255; };
    const size_t off1 = 0;
    const size_t off2 = al(off1 + sz1);
    const size_t off3 = al(off2 + sz2);
    const size_t offxp = al(off3 + sz3);
    const size_t offfb = al(offxp + (size_t)NPTS * 16);
    const size_t need = offfb + (size_t)NLVL * NPTS * 4;

    if (expected && ws_size >= need) {
        float4* blk1 = (float4*)((char*)d_ws + off1);
        float4* blk2 = (float4*)((char*)d_ws + off2);
        float4* blk3 = (float4*)((char*)d_ws + off3);
        float4* xp   = (float4*)((char*)d_ws + offxp);
        unsigned* fb = (unsigned*)((char*)d_ws + offfb);

        OptP P;
        for (int l = 0; l < NLVL; ++l) {
            P.res[l] = res[l]; P.res2[l] = res2[l];
            P.scale[l] = scale[l]; P.hi[l] = hi[l];
        }
        P.cdim1 = cdim1; P.cdim2 = cdim2; P.cdim3 = cdim3;

        repack2_kernel<<<2048, block, 0, stream>>>(x, tables, blk1, blk2, blk3, xp, P);
        passA_kernel<<<grid, block, 0, stream>>>(xp, tables, blk1, blk2, fb, P);
        mega_kernel<<<13 * 2048, block, 0, stream>>>(xp, tables, blk3, fb, P);
        assemble_t_kernel<<<NPTS / ASM_PTS, block, 0, stream>>>(fb, (float4*)out);
    } else if (expected) {
        DenseParams P;
        for (int l = 0; l < 6; ++l) {
            P.res[l] = res[l]; P.res2[l] = res2[l];
            P.scale[l] = scale[l]; P.hi[l] = hi[l];
            P.tab_off[l] = (long long)l * MAX_ENTRY * 2;
        }
        dense6_kernel<<<grid, block, 0, stream>>>(x, tables, out, P);
        for (int l = 6; l < NLVL; ++l) {
            hash_level_kernel<<<grid, block, 0, stream>>>(x, tables, out, l, scale[l], hi[l]);
        }
    } else {
        for (int l = 0; l < NLVL; ++l) {
            generic_level_kernel<<<grid, block, 0, stream>>>(
                x, tables, out, l, res[l], res2[l], use_hash[l], scale[l], hi[l]);
        }
    }
}

// Round 10
// 602.288 us; speedup vs baseline: 2.1904x; 2.1904x over previous
//
#include <hip/hip_runtime.h>
#include <math.h>

#define NLVL 16
#define MAX_ENTRY (1 << 19)
#define NPTS (1 << 20)

typedef float f2_t __attribute__((ext_vector_type(2)));
typedef float f4_t __attribute__((ext_vector_type(4)));

__device__ __forceinline__ void nt_store4(float4 v, float4* p) {
    f4_t t; t.x = v.x; t.y = v.y; t.z = v.z; t.w = v.w;
    __builtin_nontemporal_store(t, (f4_t*)p);
}
__device__ __forceinline__ void nt_storeu(unsigned v, unsigned* p) {
    __builtin_nontemporal_store(v, p);
}
__device__ __forceinline__ float4 nt_load4(const float4* p) {
    f4_t t = __builtin_nontemporal_load((const f4_t*)p);
    return make_float4(t.x, t.y, t.z, t.w);
}
__device__ __forceinline__ unsigned nt_loadu(const unsigned* p) {
    return __builtin_nontemporal_load(p);
}

// round-to-nearest-even f32 -> bf16 pair packed in u32 (a low, b high)
__device__ __forceinline__ unsigned pack_bf16(float a, float b) {
    unsigned ua = __float_as_uint(a), ub = __float_as_uint(b);
    ua = (ua + 0x7FFFu + ((ua >> 16) & 1u)) >> 16;
    ub = (ub + 0x7FFFu + ((ub >> 16) & 1u)) >> 16;
    return ua | (ub << 16);
}
__device__ __forceinline__ float bf_lo(unsigned u) { return __uint_as_float(u << 16); }
__device__ __forceinline__ float bf_hi(unsigned u) { return __uint_as_float(u & 0xFFFF0000u); }

// OFFSETS table from the reference (NOT binary order); weights in binary order.
__device__ __constant__ int OX[8] = {0, 0, 0, 0, 1, 1, 1, 1};
__device__ __constant__ int OY[8] = {0, 1, 0, 1, 0, 0, 1, 1};
__device__ __constant__ int OZ[8] = {0, 0, 1, 1, 0, 1, 0, 1};

__device__ __forceinline__ void corner_setup(
    float x0, float x1, float x2, float s, float hi,
    int& cx, int& cy, int& cz,
    float (&wx)[2], float (&wy)[2], float (&wz)[2])
{
    float c0 = fminf(fmaxf(x0 * s, 0.0f), hi);
    float c1 = fminf(fmaxf(x1 * s, 0.0f), hi);
    float c2 = fminf(fmaxf(x2 * s, 0.0f), hi);
    float f0 = floorf(c0), f1 = floorf(c1), f2 = floorf(c2);
    cx = (int)f0; cy = (int)f1; cz = (int)f2;
    float xx = c0 - f0, yy = c1 - f1, zz = c2 - f2;
    wx[0] = 1.0f - xx; wx[1] = xx;
    wy[0] = 1.0f - yy; wy[1] = yy;
    wz[0] = 1.0f - zz; wz[1] = zz;
}

// bug-compatible pair accumulate: pair j = {E(0, j&1, j>>1), E(1, j&1, j>>1)}
__device__ __forceinline__ void acc_pair(
    int j, float4 f, const float (&wx)[2], const float (&wy)[2], const float (&wz)[2],
    float& a0, float& a1)
{
    const float w0 = wx[j & 1] * wy[j >> 1] * wz[0];
    const float w1 = wx[j >> 1] * wy[j & 1] * wz[1];
    a0 += w0 * f.x + w1 * f.z;
    a1 += w0 * f.y + w1 * f.w;
}

struct OptP {
    int   res[NLVL];
    int   res2[NLVL];
    float scale[NLVL];
    float hi[NLVL];
    int   cdim[6];          // res-1 for dense levels
    long long blkoff[6];    // float4-element offsets into blk
};

// ======================= optimized path =======================

// Pack ALL dense levels 0..5 into 2x2x2 blocks (64 B/cell = 4 float4), + xp.
__global__ __launch_bounds__(256) void repack3_kernel(
    const float* __restrict__ x,
    const float* __restrict__ tables,
    float4* __restrict__ blk,
    float4* __restrict__ xp,
    OptP P)
{
    const long long stride = (long long)gridDim.x * 256;
    const long long tid = (long long)blockIdx.x * 256 + threadIdx.x;

    for (int l = 0; l < 6; ++l) {
        const int res = P.res[l], res2v = P.res2[l];
        const int cdim = P.cdim[l];
        const long long ncell = (long long)cdim * cdim * cdim;
        const float2* tab = (const float2*)(tables + (size_t)l * MAX_ENTRY * 2);
        float4* dst = blk + P.blkoff[l];
        for (long long c = tid; c < ncell; c += stride) {
            const int cx = (int)(c % cdim);
            const int cy = (int)((c / cdim) % cdim);
            const int cz = (int)(c / ((long long)cdim * cdim));
            const int base = cx + cy * res + cz * res2v;
#pragma unroll
            for (int j = 0; j < 4; ++j) {
                const int oy = j & 1, oz = j >> 1;
                const float2 e0 = tab[base + oy * res + oz * res2v];
                const float2 e1 = tab[base + 1 + oy * res + oz * res2v];
                nt_store4(make_float4(e0.x, e0.y, e1.x, e1.y), &dst[c * 4 + j]);
            }
        }
    }

    for (long long i = tid; i < NPTS; i += stride) {
        xp[i] = make_float4(x[3 * i + 0], x[3 * i + 1], x[3 * i + 2], 0.0f);
    }
}

// Mega kernel: levels 3..15, one level per 2048-block segment.
// Dense segs: 4 same-line dwordx4 from blk. Hash segs: 8 float2 gathers (cached).
// fb stream s = level s+3.
__global__ __launch_bounds__(256) void mega_kernel(
    const float4* __restrict__ xp,
    const float* __restrict__ tables,
    const float4* __restrict__ blk,
    unsigned* __restrict__ fb,
    OptP P)
{
    const int seg = blockIdx.x >> 11;
    const int lvl = seg + 3;
    const int t = (blockIdx.x & 2047) * 256 + threadIdx.x;
    unsigned* fbl = fb + (size_t)seg * NPTS;

    const float scale = P.scale[lvl], hiv = P.hi[lvl];

#pragma unroll
    for (int h = 0; h < 2; ++h) {
        const int i = t + h * (NPTS / 2);
        const float4 v = nt_load4(&xp[i]);
        int cx, cy, cz;
        float wx[2], wy[2], wz[2];
        corner_setup(v.x, v.y, v.z, scale, hiv, cx, cy, cz, wx, wy, wz);

        float a0 = 0.0f, a1 = 0.0f;

        if (lvl <= 5) {
            const int cdim = P.cdim[lvl];
            const long long c = cx + (long long)cy * cdim + (long long)cz * cdim * cdim;
            const float4* bl = blk + P.blkoff[lvl];
#pragma unroll
            for (int j = 0; j < 4; ++j) {
                const float4 f = bl[c * 4 + j];
                acc_pair(j, f, wx, wy, wz, a0, a1);
            }
        } else {
            const float2* tab = (const float2*)tables + (size_t)lvl * MAX_ENTRY;
            const unsigned P0 = 3367900313u, P1 = 2654435761u, P2 = 805459861u;
            unsigned hx[2], hy[2], hz[2];
            hx[0] = (unsigned)cx * P0; hx[1] = hx[0] + P0;
            hy[0] = (unsigned)cy * P1; hy[1] = hy[0] + P1;
            hz[0] = (unsigned)cz * P2; hz[1] = hz[0] + P2;
#pragma unroll
            for (int k = 0; k < 8; ++k) {
                const unsigned idx = (hx[OX[k]] ^ hy[OY[k]] ^ hz[OZ[k]]) & (MAX_ENTRY - 1);
                const float2 f = tab[idx];
                const float w = wx[k & 1] * wy[(k >> 1) & 1] * wz[k >> 2];
                a0 += w * f.x; a1 += w * f.y;
            }
        }

        nt_storeu(pack_bf16(a0, a1), &fbl[i]);
    }
}

// Assemble + dense levels 0..2: per 512-point block, stage fb streams 3..15 in
// LDS, compute levels 0..2 from L2-resident blk, transpose-emit out.
#define ASM_PTS 512
#define ASM_S 513
__global__ __launch_bounds__(256) void assemble2_kernel(
    const float4* __restrict__ xp,
    const float4* __restrict__ blk,
    const unsigned* __restrict__ fb,
    float4* __restrict__ out,
    OptP P)
{
    __shared__ unsigned lds[NLVL * ASM_S];
    const int base = blockIdx.x * ASM_PTS;
    const int tid = threadIdx.x;

    // stage fb streams (levels 3..15) -> rows 3..15
#pragma unroll
    for (int s = 3; s < NLVL; ++s) {
        const unsigned* f = fb + (size_t)(s - 3) * NPTS + base;
        lds[s * ASM_S + tid]       = nt_loadu(&f[tid]);
        lds[s * ASM_S + 256 + tid] = nt_loadu(&f[256 + tid]);
    }

    // compute levels 0..2 -> rows 0..2
#pragma unroll
    for (int h = 0; h < 2; ++h) {
        const int p = tid + h * 256;
        const int i = base + p;
        const float4 v = nt_load4(&xp[i]);
#pragma unroll
        for (int l = 0; l < 3; ++l) {
            int cx, cy, cz;
            float wx[2], wy[2], wz[2];
            corner_setup(v.x, v.y, v.z, P.scale[l], P.hi[l], cx, cy, cz, wx, wy, wz);
            const int cdim = P.cdim[l];
            const long long c = cx + (long long)cy * cdim + (long long)cz * cdim * cdim;
            const float4* bl = blk + P.blkoff[l];
            float a0 = 0.0f, a1 = 0.0f;
#pragma unroll
            for (int j = 0; j < 4; ++j) {
                const float4 f = bl[c * 4 + j];
                acc_pair(j, f, wx, wy, wz, a0, a1);
            }
            lds[l * ASM_S + p] = pack_bf16(a0, a1);
        }
    }

    __syncthreads();

    float4* o4 = out + (size_t)base * 8;
#pragma unroll
    for (int j = 0; j < 16; ++j) {
        const int g = j * 256 + tid;          // 0 .. 4095
        const int p = g >> 3;
        const int c = g & 7;
        const unsigned u0 = lds[(2 * c) * ASM_S + p];
        const unsigned u1 = lds[(2 * c + 1) * ASM_S + p];
        nt_store4(make_float4(bf_lo(u0), bf_hi(u0), bf_lo(u1), bf_hi(u1)), &o4[g]);
    }
}

// ======================= fallback path (round-2, known-good) =======================

struct DenseParams {
    int   res[6];
    int   res2[6];
    float scale[6];
    float hi[6];
    long long tab_off[6];
};

__device__ __forceinline__ float2 hash_point_fb(
    float x0, float x1, float x2, const float2* __restrict__ tab,
    float scale, float hi)
{
    int cx, cy, cz;
    float wx[2], wy[2], wz[2];
    corner_setup(x0, x1, x2, scale, hi, cx, cy, cz, wx, wy, wz);
    const unsigned P0 = 3367900313u, P1 = 2654435761u, P2 = 805459861u;
    unsigned hx[2], hy[2], hz[2];
    hx[0] = (unsigned)cx * P0; hx[1] = hx[0] + P0;
    hy[0] = (unsigned)cy * P1; hy[1] = hy[0] + P1;
    hz[0] = (unsigned)cz * P2; hz[1] = hz[0] + P2;
    float a0 = 0.0f, a1 = 0.0f;
#pragma unroll
    for (int k = 0; k < 8; ++k) {
        const unsigned idx = (hx[OX[k]] ^ hy[OY[k]] ^ hz[OZ[k]]) & (MAX_ENTRY - 1);
        const float2 f = tab[idx];
        const float w = wx[k & 1] * wy[(k >> 1) & 1] * wz[k >> 2];
        a0 += w * f.x; a1 += w * f.y;
    }
    return make_float2(a0, a1);
}

__global__ __launch_bounds__(256) void dense6_kernel(
    const float* __restrict__ x,
    const float* __restrict__ tables,
    float* __restrict__ out,
    DenseParams P)
{
    const int i = blockIdx.x * 256 + threadIdx.x;
    if (i >= NPTS) return;
    const float x0 = x[3 * i + 0];
    const float x1 = x[3 * i + 1];
    const float x2 = x[3 * i + 2];
    float o[12];
#pragma unroll
    for (int l = 0; l < 6; ++l) {
        int cx, cy, cz;
        float wx[2], wy[2], wz[2];
        corner_setup(x0, x1, x2, P.scale[l], P.hi[l], cx, cy, cz, wx, wy, wz);
        const float2* tab = (const float2*)(tables + P.tab_off[l]);
        const int res  = P.res[l];
        const int res2 = P.res2[l];
        const int base = cx + cy * res + cz * res2;
        float a0 = 0.0f, a1 = 0.0f;
#pragma unroll
        for (int k = 0; k < 8; ++k) {
            const int idx = base + OX[k] + OY[k] * res + OZ[k] * res2;
            const float2 f = tab[idx];
            const float w = wx[k & 1] * wy[(k >> 1) & 1] * wz[k >> 2];
            a0 += w * f.x; a1 += w * f.y;
        }
        o[2 * l + 0] = a0; o[2 * l + 1] = a1;
    }
    float4* op = (float4*)(out + (size_t)i * 32);
    op[0] = ((float4*)o)[0];
    op[1] = ((float4*)o)[1];
    op[2] = ((float4*)o)[2];
}

__global__ __launch_bounds__(256) void hash_level_kernel(
    const float* __restrict__ x,
    const float* __restrict__ tables,
    float* __restrict__ out,
    int level, float scale, float hi)
{
    const int i = blockIdx.x * 256 + threadIdx.x;
    if (i >= NPTS) return;
    const float2* tab = (const float2*)tables + (size_t)level * MAX_ENTRY;
    const float2 r = hash_point_fb(x[3 * i], x[3 * i + 1], x[3 * i + 2], tab, scale, hi);
    *(float2*)(out + (size_t)i * 32 + 2 * level) = r;
}

__global__ __launch_bounds__(256) void generic_level_kernel(
    const float* __restrict__ x,
    const float* __restrict__ tables,
    float* __restrict__ out,
    int level, int res, int res2, int use_hash, float scale, float hi)
{
    const int i = blockIdx.x * 256 + threadIdx.x;
    if (i >= NPTS) return;
    const float x0 = x[3 * i + 0];
    const float x1 = x[3 * i + 1];
    const float x2 = x[3 * i + 2];
    int cx, cy, cz;
    float wx[2], wy[2], wz[2];
    corner_setup(x0, x1, x2, scale, hi, cx, cy, cz, wx, wy, wz);
    const float2* tab = (const float2*)tables + (size_t)level * MAX_ENTRY;
    float a0 = 0.0f, a1 = 0.0f;
    if (use_hash) {
        const unsigned P0 = 3367900313u, P1 = 2654435761u, P2 = 805459861u;
        unsigned hx[2], hy[2], hz[2];
        hx[0] = (unsigned)cx * P0; hx[1] = hx[0] + P0;
        hy[0] = (unsigned)cy * P1; hy[1] = hy[0] + P1;
        hz[0] = (unsigned)cz * P2; hz[1] = hz[0] + P2;
#pragma unroll
        for (int k = 0; k < 8; ++k) {
            const unsigned idx = (hx[OX[k]] ^ hy[OY[k]] ^ hz[OZ[k]]) & (MAX_ENTRY - 1);
            const float2 f = tab[idx];
            const float w = wx[k & 1] * wy[(k >> 1) & 1] * wz[k >> 2];
            a0 += w * f.x; a1 += w * f.y;
        }
    } else {
        const int base = cx + cy * res + cz * res2;
#pragma unroll
        for (int k = 0; k < 8; ++k) {
            const int idx = base + OX[k] + OY[k] * res + OZ[k] * res2;
            const float2 f = tab[idx];
            const float w = wx[k & 1] * wy[(k >> 1) & 1] * wz[k >> 2];
            a0 += w * f.x; a1 += w * f.y;
        }
    }
    *(float2*)(out + (size_t)i * 32 + 2 * level) = make_float2(a0, a1);
}

// ======================= launch =======================

extern "C" void kernel_launch(void* const* d_in, const int* in_sizes, int n_in,
                              void* d_out, int out_size, void* d_ws, size_t ws_size,
                              hipStream_t stream)
{
    const float* x      = (const float*)d_in[0];
    const float* tables = (const float*)d_in[1];
    float* out          = (float*)d_out;

    // Reproduce numpy's resolution computation bit-for-bit (same libm).
    int   res[NLVL], res2[NLVL], use_hash[NLVL];
    float scale[NLVL], hi[NLVL];
    const double b = exp((log(2048.0) - log(16.0)) / 15.0);
    for (int l = 0; l < NLVL; ++l) {
        const int r = (int)floor(16.0 * pow(b, (double)l));
        res[l]  = r;
        res2[l] = r * r;
        const long long t3 = (long long)r * r * r;
        use_hash[l] = (t3 >= (long long)MAX_ENTRY) ? 1 : 0;
        scale[l] = (float)(r - 1);
        hi[l]    = (float)((double)r - 1.0001);
    }

    const int block = 256;
    const int grid  = (NPTS + block - 1) / block;

    bool expected = true;
    for (int l = 0; l < 6; ++l)    expected = expected && !use_hash[l];
    for (int l = 6; l < NLVL; ++l) expected = expected && use_hash[l];

    // Workspace layout: blk (dense 0..5, 2x2x2 64B cells) | xp | fb (13 streams)
    long long blkoff[6];
    long long blkTot = 0;   // in float4 elements
    for (int l = 0; l < 6; ++l) {
        const long long cd = (long long)res[l] - 1;
        blkoff[l] = blkTot;
        blkTot += cd * cd * cd * 4;
    }
    auto al = [](size_t v) { return (v + 255) & ~(size_t)255; };
    const size_t blkBytes = (size_t)blkTot * 16;
    const size_t offxp = al(blkBytes);
    const size_t offfb = al(offxp + (size_t)NPTS * 16);
    const size_t need  = offfb + (size_t)13 * NPTS * 4;

    if (expected && ws_size >= need) {
        float4* blk  = (float4*)d_ws;
        float4* xp   = (float4*)((char*)d_ws + offxp);
        unsigned* fb = (unsigned*)((char*)d_ws + offfb);

        OptP P;
        for (int l = 0; l < NLVL; ++l) {
            P.res[l] = res[l]; P.res2[l] = res2[l];
            P.scale[l] = scale[l]; P.hi[l] = hi[l];
        }
        for (int l = 0; l < 6; ++l) { P.cdim[l] = res[l] - 1; P.blkoff[l] = blkoff[l]; }

        repack3_kernel<<<2048, block, 0, stream>>>(x, tables, blk, xp, P);
        mega_kernel<<<13 * 2048, block, 0, stream>>>(xp, tables, blk, fb, P);
        assemble2_kernel<<<NPTS / ASM_PTS, block, 0, stream>>>(xp, blk, fb, (float4*)out, P);
    } else if (expected) {
        DenseParams P;
        for (int l = 0; l < 6; ++l) {
            P.res[l] = res[l]; P.res2[l] = res2[l];
            P.scale[l] = scale[l]; P.hi[l] = hi[l];
            P.tab_off[l] = (long long)l * MAX_ENTRY * 2;
        }
        dense6_kernel<<<grid, block, 0, stream>>>(x, tables, out, P);
        for (int l = 6; l < NLVL; ++l) {
            hash_level_kernel<<<grid, block, 0, stream>>>(x, tables, out, l, scale[l], hi[l]);
        }
    } else {
        for (int l = 0; l < NLVL; ++l) {
            generic_level_kernel<<<grid, block, 0, stream>>>(
                x, tables, out, l, res[l], res2[l], use_hash[l], scale[l], hi[l]);
        }
    }
}

// Round 11
// 552.366 us; speedup vs baseline: 2.3884x; 1.0904x over previous
//
#include <hip/hip_runtime.h>
#include <math.h>

#define NLVL 16
#define MAX_ENTRY (1 << 19)
#define NPTS (1 << 20)

typedef float f2_t __attribute__((ext_vector_type(2)));
typedef float f4_t __attribute__((ext_vector_type(4)));

__device__ __forceinline__ void nt_store4(float4 v, float4* p) {
    f4_t t; t.x = v.x; t.y = v.y; t.z = v.z; t.w = v.w;
    __builtin_nontemporal_store(t, (f4_t*)p);
}
__device__ __forceinline__ void nt_storeu(unsigned v, unsigned* p) {
    __builtin_nontemporal_store(v, p);
}
__device__ __forceinline__ float4 nt_load4(const float4* p) {
    f4_t t = __builtin_nontemporal_load((const f4_t*)p);
    return make_float4(t.x, t.y, t.z, t.w);
}
__device__ __forceinline__ unsigned nt_loadu(const unsigned* p) {
    return __builtin_nontemporal_load(p);
}

// round-to-nearest-even f32 -> bf16 pair packed in u32 (a low, b high)
__device__ __forceinline__ unsigned pack_bf16(float a, float b) {
    unsigned ua = __float_as_uint(a), ub = __float_as_uint(b);
    ua = (ua + 0x7FFFu + ((ua >> 16) & 1u)) >> 16;
    ub = (ub + 0x7FFFu + ((ub >> 16) & 1u)) >> 16;
    return ua | (ub << 16);
}
__device__ __forceinline__ float bf_lo(unsigned u) { return __uint_as_float(u << 16); }
__device__ __forceinline__ float bf_hi(unsigned u) { return __uint_as_float(u & 0xFFFF0000u); }

// OFFSETS table from the reference (NOT binary order); weights in binary order.
__device__ __constant__ int OX[8] = {0, 0, 0, 0, 1, 1, 1, 1};
__device__ __constant__ int OY[8] = {0, 1, 0, 1, 0, 0, 1, 1};
__device__ __constant__ int OZ[8] = {0, 0, 1, 1, 0, 1, 0, 1};

__device__ __forceinline__ void corner_setup(
    float x0, float x1, float x2, float s, float hi,
    int& cx, int& cy, int& cz,
    float (&wx)[2], float (&wy)[2], float (&wz)[2])
{
    float c0 = fminf(fmaxf(x0 * s, 0.0f), hi);
    float c1 = fminf(fmaxf(x1 * s, 0.0f), hi);
    float c2 = fminf(fmaxf(x2 * s, 0.0f), hi);
    float f0 = floorf(c0), f1 = floorf(c1), f2 = floorf(c2);
    cx = (int)f0; cy = (int)f1; cz = (int)f2;
    float xx = c0 - f0, yy = c1 - f1, zz = c2 - f2;
    wx[0] = 1.0f - xx; wx[1] = xx;
    wy[0] = 1.0f - yy; wy[1] = yy;
    wz[0] = 1.0f - zz; wz[1] = zz;
}

// bug-compatible pair accumulate: pair j = {E(0, j&1, j>>1), E(1, j&1, j>>1)}
__device__ __forceinline__ void acc_pair(
    int j, float4 f, const float (&wx)[2], const float (&wy)[2], const float (&wz)[2],
    float& a0, float& a1)
{
    const float w0 = wx[j & 1] * wy[j >> 1] * wz[0];
    const float w1 = wx[j >> 1] * wy[j & 1] * wz[1];
    a0 += w0 * f.x + w1 * f.z;
    a1 += w0 * f.y + w1 * f.w;
}

struct OptP {
    int   res[NLVL];
    int   res2[NLVL];
    float scale[NLVL];
    float hi[NLVL];
    int   cdim[6];          // res-1 for dense levels
    long long blkoff[6];    // float4-element offsets into blk
};

// ======================= optimized path =======================

// Pack ALL dense levels 0..5 into 2x2x2 blocks (64 B/cell = 4 float4), + xp.
// Cached stores: blk levels 0..4 (~2.6 MB) and xp (16 MB) should L2-persist
// into mega.
__global__ __launch_bounds__(256) void repack3_kernel(
    const float* __restrict__ x,
    const float* __restrict__ tables,
    float4* __restrict__ blk,
    float4* __restrict__ xp,
    OptP P)
{
    const long long stride = (long long)gridDim.x * 256;
    const long long tid = (long long)blockIdx.x * 256 + threadIdx.x;

    for (int l = 0; l < 6; ++l) {
        const int res = P.res[l], res2v = P.res2[l];
        const int cdim = P.cdim[l];
        const long long ncell = (long long)cdim * cdim * cdim;
        const float2* tab = (const float2*)(tables + (size_t)l * MAX_ENTRY * 2);
        float4* dst = blk + P.blkoff[l];
        for (long long c = tid; c < ncell; c += stride) {
            const int cx = (int)(c % cdim);
            const int cy = (int)((c / cdim) % cdim);
            const int cz = (int)(c / ((long long)cdim * cdim));
            const int base = cx + cy * res + cz * res2v;
#pragma unroll
            for (int j = 0; j < 4; ++j) {
                const int oy = j & 1, oz = j >> 1;
                const float2 e0 = tab[base + oy * res + oz * res2v];
                const float2 e1 = tab[base + 1 + oy * res + oz * res2v];
                dst[c * 4 + j] = make_float4(e0.x, e0.y, e1.x, e1.y);
            }
        }
    }

    for (long long i = tid; i < NPTS; i += stride) {
        xp[i] = make_float4(x[3 * i + 0], x[3 * i + 1], x[3 * i + 2], 0.0f);
    }
}

// Mega kernel: ALL 16 levels, one level per 2048-block segment.
// Dense segs (0..5): 4 same-line dwordx4 from blk. Hash segs (6..15): 8 cached
// float2 gathers. fb stream s = level s.
__global__ __launch_bounds__(256) void mega_kernel(
    const float4* __restrict__ xp,
    const float* __restrict__ tables,
    const float4* __restrict__ blk,
    unsigned* __restrict__ fb,
    OptP P)
{
    const int lvl = blockIdx.x >> 11;
    const int t = (blockIdx.x & 2047) * 256 + threadIdx.x;
    unsigned* fbl = fb + (size_t)lvl * NPTS;

    const float scale = P.scale[lvl], hiv = P.hi[lvl];

#pragma unroll
    for (int h = 0; h < 2; ++h) {
        const int i = t + h * (NPTS / 2);
        const float4 v = nt_load4(&xp[i]);
        int cx, cy, cz;
        float wx[2], wy[2], wz[2];
        corner_setup(v.x, v.y, v.z, scale, hiv, cx, cy, cz, wx, wy, wz);

        float a0 = 0.0f, a1 = 0.0f;

        if (lvl <= 5) {
            const int cdim = P.cdim[lvl];
            const long long c = cx + (long long)cy * cdim + (long long)cz * cdim * cdim;
            const float4* bl = blk + P.blkoff[lvl];
#pragma unroll
            for (int j = 0; j < 4; ++j) {
                const float4 f = bl[c * 4 + j];
                acc_pair(j, f, wx, wy, wz, a0, a1);
            }
        } else {
            const float2* tab = (const float2*)tables + (size_t)lvl * MAX_ENTRY;
            const unsigned P0 = 3367900313u, P1 = 2654435761u, P2 = 805459861u;
            unsigned hx[2], hy[2], hz[2];
            hx[0] = (unsigned)cx * P0; hx[1] = hx[0] + P0;
            hy[0] = (unsigned)cy * P1; hy[1] = hy[0] + P1;
            hz[0] = (unsigned)cz * P2; hz[1] = hz[0] + P2;
#pragma unroll
            for (int k = 0; k < 8; ++k) {
                const unsigned idx = (hx[OX[k]] ^ hy[OY[k]] ^ hz[OZ[k]]) & (MAX_ENTRY - 1);
                const float2 f = tab[idx];
                const float w = wx[k & 1] * wy[(k >> 1) & 1] * wz[k >> 2];
                a0 += w * f.x; a1 += w * f.y;
            }
        }

        nt_storeu(pack_bf16(a0, a1), &fbl[i]);
    }
}

// Pure LDS-transpose assemble: 16 coalesced stream reads -> coalesced out.
#define ASM_PTS 512
#define ASM_S 513
__global__ __launch_bounds__(256) void assemble_t_kernel(
    const unsigned* __restrict__ fb, float4* __restrict__ out)
{
    __shared__ unsigned lds[NLVL * ASM_S];
    const int base = blockIdx.x * ASM_PTS;
    const int tid = threadIdx.x;

#pragma unroll
    for (int s = 0; s < NLVL; ++s) {
        const unsigned* f = fb + (size_t)s * NPTS + base;
        lds[s * ASM_S + tid]       = nt_loadu(&f[tid]);
        lds[s * ASM_S + 256 + tid] = nt_loadu(&f[256 + tid]);
    }
    __syncthreads();

    float4* o4 = out + (size_t)base * 8;
#pragma unroll
    for (int j = 0; j < 16; ++j) {
        const int g = j * 256 + tid;          // 0 .. 4095
        const int p = g >> 3;
        const int c = g & 7;
        const unsigned u0 = lds[(2 * c) * ASM_S + p];
        const unsigned u1 = lds[(2 * c + 1) * ASM_S + p];
        nt_store4(make_float4(bf_lo(u0), bf_hi(u0), bf_lo(u1), bf_hi(u1)), &o4[g]);
    }
}

// ======================= fallback path (round-2, known-good) =======================

struct DenseParams {
    int   res[6];
    int   res2[6];
    float scale[6];
    float hi[6];
    long long tab_off[6];
};

__device__ __forceinline__ float2 hash_point_fb(
    float x0, float x1, float x2, const float2* __restrict__ tab,
    float scale, float hi)
{
    int cx, cy, cz;
    float wx[2], wy[2], wz[2];
    corner_setup(x0, x1, x2, scale, hi, cx, cy, cz, wx, wy, wz);
    const unsigned P0 = 3367900313u, P1 = 2654435761u, P2 = 805459861u;
    unsigned hx[2], hy[2], hz[2];
    hx[0] = (unsigned)cx * P0; hx[1] = hx[0] + P0;
    hy[0] = (unsigned)cy * P1; hy[1] = hy[0] + P1;
    hz[0] = (unsigned)cz * P2; hz[1] = hz[0] + P2;
    float a0 = 0.0f, a1 = 0.0f;
#pragma unroll
    for (int k = 0; k < 8; ++k) {
        const unsigned idx = (hx[OX[k]] ^ hy[OY[k]] ^ hz[OZ[k]]) & (MAX_ENTRY - 1);
        const float2 f = tab[idx];
        const float w = wx[k & 1] * wy[(k >> 1) & 1] * wz[k >> 2];
        a0 += w * f.x; a1 += w * f.y;
    }
    return make_float2(a0, a1);
}

__global__ __launch_bounds__(256) void dense6_kernel(
    const float* __restrict__ x,
    const float* __restrict__ tables,
    float* __restrict__ out,
    DenseParams P)
{
    const int i = blockIdx.x * 256 + threadIdx.x;
    if (i >= NPTS) return;
    const float x0 = x[3 * i + 0];
    const float x1 = x[3 * i + 1];
    const float x2 = x[3 * i + 2];
    float o[12];
#pragma unroll
    for (int l = 0; l < 6; ++l) {
        int cx, cy, cz;
        float wx[2], wy[2], wz[2];
        corner_setup(x0, x1, x2, P.scale[l], P.hi[l], cx, cy, cz, wx, wy, wz);
        const float2* tab = (const float2*)(tables + P.tab_off[l]);
        const int res  = P.res[l];
        const int res2 = P.res2[l];
        const int base = cx + cy * res + cz * res2;
        float a0 = 0.0f, a1 = 0.0f;
#pragma unroll
        for (int k = 0; k < 8; ++k) {
            const int idx = base + OX[k] + OY[k] * res + OZ[k] * res2;
            const float2 f = tab[idx];
            const float w = wx[k & 1] * wy[(k >> 1) & 1] * wz[k >> 2];
            a0 += w * f.x; a1 += w * f.y;
        }
        o[2 * l + 0] = a0; o[2 * l + 1] = a1;
    }
    float4* op = (float4*)(out + (size_t)i * 32);
    op[0] = ((float4*)o)[0];
    op[1] = ((float4*)o)[1];
    op[2] = ((float4*)o)[2];
}

__global__ __launch_bounds__(256) void hash_level_kernel(
    const float* __restrict__ x,
    const float* __restrict__ tables,
    float* __restrict__ out,
    int level, float scale, float hi)
{
    const int i = blockIdx.x * 256 + threadIdx.x;
    if (i >= NPTS) return;
    const float2* tab = (const float2*)tables + (size_t)level * MAX_ENTRY;
    const float2 r = hash_point_fb(x[3 * i], x[3 * i + 1], x[3 * i + 2], tab, scale, hi);
    *(float2*)(out + (size_t)i * 32 + 2 * level) = r;
}

__global__ __launch_bounds__(256) void generic_level_kernel(
    const float* __restrict__ x,
    const float* __restrict__ tables,
    float* __restrict__ out,
    int level, int res, int res2, int use_hash, float scale, float hi)
{
    const int i = blockIdx.x * 256 + threadIdx.x;
    if (i >= NPTS) return;
    const float x0 = x[3 * i + 0];
    const float x1 = x[3 * i + 1];
    const float x2 = x[3 * i + 2];
    int cx, cy, cz;
    float wx[2], wy[2], wz[2];
    corner_setup(x0, x1, x2, scale, hi, cx, cy, cz, wx, wy, wz);
    const float2* tab = (const float2*)tables + (size_t)level * MAX_ENTRY;
    float a0 = 0.0f, a1 = 0.0f;
    if (use_hash) {
        const unsigned P0 = 3367900313u, P1 = 2654435761u, P2 = 805459861u;
        unsigned hx[2], hy[2], hz[2];
        hx[0] = (unsigned)cx * P0; hx[1] = hx[0] + P0;
        hy[0] = (unsigned)cy * P1; hy[1] = hy[0] + P1;
        hz[0] = (unsigned)cz * P2; hz[1] = hz[0] + P2;
#pragma unroll
        for (int k = 0; k < 8; ++k) {
            const unsigned idx = (hx[OX[k]] ^ hy[OY[k]] ^ hz[OZ[k]]) & (MAX_ENTRY - 1);
            const float2 f = tab[idx];
            const float w = wx[k & 1] * wy[(k >> 1) & 1] * wz[k >> 2];
            a0 += w * f.x; a1 += w * f.y;
        }
    } else {
        const int base = cx + cy * res + cz * res2;
#pragma unroll
        for (int k = 0; k < 8; ++k) {
            const int idx = base + OX[k] + OY[k] * res + OZ[k] * res2;
            const float2 f = tab[idx];
            const float w = wx[k & 1] * wy[(k >> 1) & 1] * wz[k >> 2];
            a0 += w * f.x; a1 += w * f.y;
        }
    }
    *(float2*)(out + (size_t)i * 32 + 2 * level) = make_float2(a0, a1);
}

// ======================= launch =======================

extern "C" void kernel_launch(void* const* d_in, const int* in_sizes, int n_in,
                              void* d_out, int out_size, void* d_ws, size_t ws_size,
                              hipStream_t stream)
{
    const float* x      = (const float*)d_in[0];
    const float* tables = (const float*)d_in[1];
    float* out          = (float*)d_out;

    // Reproduce numpy's resolution computation bit-for-bit (same libm).
    int   res[NLVL], res2[NLVL], use_hash[NLVL];
    float scale[NLVL], hi[NLVL];
    const double b = exp((log(2048.0) - log(16.0)) / 15.0);
    for (int l = 0; l < NLVL; ++l) {
        const int r = (int)floor(16.0 * pow(b, (double)l));
        res[l]  = r;
        res2[l] = r * r;
        const long long t3 = (long long)r * r * r;
        use_hash[l] = (t3 >= (long long)MAX_ENTRY) ? 1 : 0;
        scale[l] = (float)(r - 1);
        hi[l]    = (float)((double)r - 1.0001);
    }

    const int block = 256;
    const int grid  = (NPTS + block - 1) / block;

    bool expected = true;
    for (int l = 0; l < 6; ++l)    expected = expected && !use_hash[l];
    for (int l = 6; l < NLVL; ++l) expected = expected && use_hash[l];

    // Workspace layout: blk (dense 0..5, 2x2x2 64B cells) | xp | fb (16 streams)
    long long blkoff[6];
    long long blkTot = 0;   // in float4 elements
    for (int l = 0; l < 6; ++l) {
        const long long cd = (long long)res[l] - 1;
        blkoff[l] = blkTot;
        blkTot += cd * cd * cd * 4;
    }
    auto al = [](size_t v) { return (v + 255) & ~(size_t)255; };
    const size_t blkBytes = (size_t)blkTot * 16;
    const size_t offxp = al(blkBytes);
    const size_t offfb = al(offxp + (size_t)NPTS * 16);
    const size_t need  = offfb + (size_t)NLVL * NPTS * 4;

    if (expected && ws_size >= need) {
        float4* blk  = (float4*)d_ws;
        float4* xp   = (float4*)((char*)d_ws + offxp);
        unsigned* fb = (unsigned*)((char*)d_ws + offfb);

        OptP P;
        for (int l = 0; l < NLVL; ++l) {
            P.res[l] = res[l]; P.res2[l] = res2[l];
            P.scale[l] = scale[l]; P.hi[l] = hi[l];
        }
        for (int l = 0; l < 6; ++l) { P.cdim[l] = res[l] - 1; P.blkoff[l] = blkoff[l]; }

        repack3_kernel<<<4096, block, 0, stream>>>(x, tables, blk, xp, P);
        mega_kernel<<<NLVL * 2048, block, 0, stream>>>(xp, tables, blk, fb, P);
        assemble_t_kernel<<<NPTS / ASM_PTS, block, 0, stream>>>(fb, (float4*)out);
    } else if (expected) {
        DenseParams P;
        for (int l = 0; l < 6; ++l) {
            P.res[l] = res[l]; P.res2[l] = res2[l];
            P.scale[l] = scale[l]; P.hi[l] = hi[l];
            P.tab_off[l] = (long long)l * MAX_ENTRY * 2;
        }
        dense6_kernel<<<grid, block, 0, stream>>>(x, tables, out, P);
        for (int l = 6; l < NLVL; ++l) {
            hash_level_kernel<<<grid, block, 0, stream>>>(x, tables, out, l, scale[l], hi[l]);
        }
    } else {
        for (int l = 0; l < NLVL; ++l) {
            generic_level_kernel<<<grid, block, 0, stream>>>(
                x, tables, out, l, res[l], res2[l], use_hash[l], scale[l], hi[l]);
        }
    }
}